// Round 8
// baseline (99.716 us; speedup 1.0000x reference)
//
#include <hip/hip_runtime.h>

#define F_N 100000
#define V_N 30000
#define DD 15          // domain size D
#define DP 16          // padded row stride (64 B / cacheline)
#define TILE 225       // D*D
#define T_N (2 * F_N)  // 200000 f2v messages
#define NSLOT 256
#define CAP 32         // bucket capacity per variable

// ---- workspace layout (float offsets) ----
static const size_t M_OFF     = 0;          // float[T_N*DP]  = 3,200,000
static const size_t DIST_OFF  = 3200000;    // float[V_N*DP]  = 480,000
static const size_t CNT_OFF   = 3680000;    // int[V_N]
static const size_t TLIST_OFF = 3710048;    // int[V_N*CAP]   = 960,000
static const size_t AMAX_OFF  = 4670048;    // int[V_N]
static const size_t SLOTP_OFF = 4700064;    // float[NSLOT]
static const size_t SLOTC_OFF = 4700320;    // float[NSLOT]
static const size_t SLOTE_OFF = 4700576;    // float[NSLOT]

__global__ void k_init(int* __restrict__ cnt, float* __restrict__ slots) {
    int i = blockIdx.x * blockDim.x + threadIdx.x;
    if (i < V_N) cnt[i] = 0;
    if (i < 3 * NSLOT) slots[i] = 0.0f;   // slotP, slotC, slotE (contiguous)
}

// Bucket-place: invert the scatter with one int atomic per message
// (spread over 30k counter addresses -> no hotspot).
__global__ void k_place(const int* __restrict__ scat,
                        int* __restrict__ cnt,
                        int* __restrict__ tlist) {
    int t = blockIdx.x * blockDim.x + threadIdx.x;
    if (t < T_N) {
        int v = scat[t];
        int pos = atomicAdd(&cnt[v], 1);
        if (pos < CAP) tlist[v * CAP + pos] = t;
    }
}

// 16 lanes per factor, all-register. Lane m holds COLUMN m of the 15x15 tile
// (15 independent coalesced loads -> deep MLP, no LDS, no barrier).
//   m_f2rv[f][i] = min_j (C[i][j] + mcv[j])  : butterfly min over lanes
//   m_f2cv[f][j] = min_i (C[i][j] + mrv[i])  : local chain with shfl'd mrv
__global__ __launch_bounds__(256) void k_minplus(
        const float* __restrict__ msgs,
        const float* __restrict__ cost,
        float* __restrict__ m_arr) {
    int tid = threadIdx.x;
    int g   = tid >> 4;                   // group 0..15
    int m   = tid & 15;                   // lane within group
    int f   = blockIdx.x * 16 + g;        // 6250 blocks * 16 = F_N exactly
    bool act = (m < DD);
    const float* Cf = cost + (size_t)f * TILE;
    float v[DD];
#pragma unroll
    for (int k = 0; k < DD; ++k)
        v[k] = act ? Cf[k * DD + m] : 0.0f;          // column m, 15 indep loads
    float mcv = act ? msgs[(size_t)(F_N + f) * DD + m] : 0.0f;   // mcv[m]
    float mrv = act ? msgs[(size_t)f * DD + m]       : 1e30f;    // mrv[m]
    // col-min_m = min_k (v[k] + mrv[k])
    float cm = 1e30f;
#pragma unroll
    for (int k = 0; k < DD; ++k) {
        float mrvk = __shfl(mrv, k, 16);
        cm = fminf(cm, v[k] + mrvk);
    }
    // row-min_k: butterfly over 16 lanes of (v[k] + mcv_lane); lane k keeps it
    float rsel = 0.0f;
#pragma unroll
    for (int k = 0; k < DD; ++k) {
        float t = act ? (v[k] + mcv) : 1e30f;
#pragma unroll
        for (int off = 1; off < 16; off <<= 1)
            t = fminf(t, __shfl_xor(t, off, 16));
        if (m == k) rsel = t;
    }
    if (act) {
        m_arr[(size_t)f * DP + m]         = rsel;    // m_f2rv row f
        m_arr[(size_t)(F_N + f) * DP + m] = cm;      // m_f2cv row f
    }
}

// 16 lanes per variable: lane k owns belief[k]. Bucket indices prefetched
// (coalesced) and broadcast via shfl; m-row loads independent.
// Softmax/entropy/argmax via width-16 shfl_xor butterflies.
// Entropy: wave reduce -> LDS -> ONE atomic per block into 256 spread slots.
__global__ __launch_bounds__(256) void k_gather_softmax(
        const float* __restrict__ m,
        const int* __restrict__ cnt,
        const int* __restrict__ tlist,
        float* __restrict__ dist,
        int*   __restrict__ amax,
        float* __restrict__ slotE) {
    int gid = blockIdx.x * 256 + threadIdx.x;
    int v = gid >> 4;
    int k = gid & 15;
    bool act = (v < V_N) && (k < DD);
    float b0 = 0.0f, b1 = 0.0f;
    if (v < V_N) {
        int n = cnt[v];
        if (n > CAP) n = CAP;
        int n1 = (n < 16) ? n : 16;
        int tl  = (k < n)       ? tlist[v * CAP + k]      : 0;
        int tl2 = (k + 16 < n)  ? tlist[v * CAP + k + 16] : 0;
        int i = 0;
        for (; i + 1 < n1; i += 2) {
            int ta = __shfl(tl, i, 16);
            int tb = __shfl(tl, i + 1, 16);
            if (k < DD) {
                b0 += m[(size_t)ta * DP + k];
                b1 += m[(size_t)tb * DP + k];
            }
        }
        if (i < n1) {
            int ta = __shfl(tl, i, 16);
            if (k < DD) b0 += m[(size_t)ta * DP + k];
        }
        for (int j = 16; j < n; ++j) {          // rare: deg > 16
            int ta = __shfl(tl2, j - 16, 16);
            if (k < DD) b1 += m[(size_t)ta * DP + k];
        }
    }
    float b = b0 + b1;
    float bm = act ? b : 1e30f;
#pragma unroll
    for (int off = 1; off < 16; off <<= 1) bm = fminf(bm, __shfl_xor(bm, off, 16));
    float e = act ? expf(bm - b) : 0.0f;
    float den = e;
#pragma unroll
    for (int off = 1; off < 16; off <<= 1) den += __shfl_xor(den, off, 16);
    float dk = e / den;
    float entp = 0.0f;
    if (act) {
        dist[(size_t)v * DP + k] = dk;
        entp = -dk * log2f(dk + 1e-6f);
    }
    // argmax with first-max (lowest index on tie) semantics
    float av = act ? dk : -1.0f;
    int   ai = k;
#pragma unroll
    for (int off = 1; off < 16; off <<= 1) {
        float ov = __shfl_xor(av, off, 16);
        int   oi = __shfl_xor(ai, off, 16);
        if (ov > av || (ov == av && oi < ai)) { av = ov; ai = oi; }
    }
    if (k == 0 && v < V_N) amax[v] = ai;
#pragma unroll
    for (int off = 32; off > 0; off >>= 1) entp += __shfl_down(entp, off, 64);
    __shared__ float sE[4];
    if ((threadIdx.x & 63) == 0) sE[threadIdx.x >> 6] = entp;
    __syncthreads();
    if (threadIdx.x == 0)
        atomicAdd(&slotE[blockIdx.x & (NSLOT - 1)], sE[0] + sE[1] + sE[2] + sE[3]);
}

// One wave per factor: per_f = drv^T C dcv, cost = C[amax,amax].
// dist rows loaded ONCE (broadcast cacheline), spread to elements via shfl.
__global__ __launch_bounds__(256) void k_factor_loss(
        const float* __restrict__ cost,
        const float* __restrict__ dist,
        const int*   __restrict__ amax,
        const int*   __restrict__ rv_idx,
        const int*   __restrict__ cv_idx,
        float* __restrict__ slotP,
        float* __restrict__ slotC) {
    int gtid = blockIdx.x * 256 + threadIdx.x;
    int f    = gtid >> 6;
    int lane = threadIdx.x & 63;
    float s = 0.0f, c = 0.0f;
    if (f < F_N) {
        int rv = rv_idx[f], cv = cv_idx[f];
        float drv = dist[(size_t)rv * DP + (lane & 15)];
        float dcv = dist[(size_t)cv * DP + (lane & 15)];
        const float* Cf = cost + (size_t)f * TILE;
#pragma unroll
        for (int t = 0; t < 4; ++t) {
            int e = lane + t * 64;
            if (e < TILE) {
                int i = e / DD;
                int j = e - i * DD;
                s += __shfl(drv, i, 64) * Cf[e] * __shfl(dcv, j, 64);
            }
        }
        if (lane == 0) c = Cf[amax[rv] * DD + amax[cv]];
    }
#pragma unroll
    for (int off = 32; off > 0; off >>= 1) s += __shfl_down(s, off, 64);
    __shared__ float sP[4], sC[4];
    int w = threadIdx.x >> 6;
    if (lane == 0) { sP[w] = s; sC[w] = c; }
    __syncthreads();
    if (threadIdx.x == 0) {
        float tp = sP[0] + sP[1] + sP[2] + sP[3];
        float tc = sC[0] + sC[1] + sC[2] + sC[3];
        int slot = blockIdx.x & (NSLOT - 1);
        atomicAdd(&slotP[slot], tp);
        atomicAdd(&slotC[slot], tc);
    }
}

__global__ void k_final(const float* __restrict__ slotP,
                        const float* __restrict__ slotC,
                        const float* __restrict__ slotE,
                        float* __restrict__ out) {
    int t = threadIdx.x;   // 256 threads
    float p = slotP[t], c = slotC[t], g = slotE[t];
#pragma unroll
    for (int off = 32; off > 0; off >>= 1) {
        p += __shfl_down(p, off, 64);
        c += __shfl_down(c, off, 64);
        g += __shfl_down(g, off, 64);
    }
    __shared__ float sp[4], sc[4], se[4];
    if ((t & 63) == 0) { sp[t >> 6] = p; sc[t >> 6] = c; se[t >> 6] = g; }
    __syncthreads();
    if (t == 0) {
        float tp = sp[0] + sp[1] + sp[2] + sp[3];
        float tc = sc[0] + sc[1] + sc[2] + sc[3];
        float te = se[0] + se[1] + se[2] + se[3];
        out[0] = tp + 0.1f * (te / (float)V_N);
        out[1] = tc;
    }
}

extern "C" void kernel_launch(void* const* d_in, const int* in_sizes, int n_in,
                              void* d_out, int out_size, void* d_ws, size_t ws_size,
                              hipStream_t stream) {
    const float* msgs = (const float*)d_in[0];   // (4*F_N, 15)
    const float* cost = (const float*)d_in[1];   // (F_N, 15, 15)
    const int* scat   = (const int*)d_in[46];    // f2v_per_v_scatter_idxes (2*F_N)
    const int* rv     = (const int*)d_in[48];    // rv_idxes (F_N)
    const int* cv     = (const int*)d_in[49];    // cv_idxes (F_N)

    float* ws    = (float*)d_ws;
    float* m     = ws + M_OFF;
    float* dist  = ws + DIST_OFF;
    int*   cnt   = (int*)(ws + CNT_OFF);
    int*   tlist = (int*)(ws + TLIST_OFF);
    int*   amax  = (int*)(ws + AMAX_OFF);
    float* slotP = ws + SLOTP_OFF;
    float* slotC = ws + SLOTC_OFF;
    float* slotE = ws + SLOTE_OFF;
    float* out   = (float*)d_out;

    k_init<<<(V_N + 255) / 256, 256, 0, stream>>>(cnt, slotP);
    k_place<<<(T_N + 255) / 256, 256, 0, stream>>>(scat, cnt, tlist);
    k_minplus<<<F_N / 16, 256, 0, stream>>>(msgs, cost, m);
    k_gather_softmax<<<(V_N * 16 + 255) / 256, 256, 0, stream>>>(m, cnt, tlist, dist, amax, slotE);
    k_factor_loss<<<(F_N * 64 + 255) / 256, 256, 0, stream>>>(cost, dist, amax, rv, cv, slotP, slotC);
    k_final<<<1, 256, 0, stream>>>(slotP, slotC, slotE, out);
}

// Round 9
// 94.509 us; speedup vs baseline: 1.0551x; 1.0551x over previous
//
#include <hip/hip_runtime.h>

#define F_N 100000
#define V_N 30000
#define DD 15          // domain size D
#define DP 16          // padded row stride (64 B / cacheline)
#define TILE 225       // D*D
#define T_N (2 * F_N)  // 200000 f2v messages
#define NSLOT 256
#define MPB 16         // factors per block in minplus kernel
#define CAP 32         // bucket capacity per variable

// ---- workspace layout (float offsets) ----
static const size_t M_OFF     = 0;          // float[T_N*DP]  = 3,200,000
static const size_t DIST_OFF  = 3200000;    // float[V_N*DP]  = 480,000
static const size_t CNT_OFF   = 3680000;    // int[V_N]
static const size_t TLIST_OFF = 3710048;    // int[V_N*CAP]   = 960,000
static const size_t AMAX_OFF  = 4670048;    // int[V_N]
static const size_t SLOTP_OFF = 4700064;    // float[NSLOT]
static const size_t SLOTC_OFF = 4700320;    // float[NSLOT]
static const size_t SLOTE_OFF = 4700576;    // float[NSLOT]

__global__ void k_init(int* __restrict__ cnt, float* __restrict__ slots) {
    int i = blockIdx.x * blockDim.x + threadIdx.x;
    if (i < V_N) cnt[i] = 0;
    if (i < 3 * NSLOT) slots[i] = 0.0f;   // slotP, slotC, slotE (contiguous)
}

// Bucket-place: invert the scatter with one int atomic per message
// (spread over 30k counter addresses -> no hotspot).
__global__ void k_place(const int* __restrict__ scat,
                        int* __restrict__ cnt,
                        int* __restrict__ tlist) {
    int t = blockIdx.x * blockDim.x + threadIdx.x;
    if (t < T_N) {
        int v = scat[t];
        int pos = atomicAdd(&cnt[v], 1);
        if (pos < CAP) tlist[v * CAP + pos] = t;
    }
}

// Block handles 16 factors. Staging is MANUALLY 4-deep unrolled float4:
// 3 unconditional + 1 predicated load into REGISTERS (4 outstanding vmem/lane),
// then ds_writes + one barrier. Compute: 15 row-mins + 15 col-mins per factor.
__global__ __launch_bounds__(256) void k_minplus(
        const float* __restrict__ msgs,
        const float* __restrict__ cost,
        float* __restrict__ m_arr) {
    __shared__ __align__(16) float tile[MPB * TILE];   // 3600 floats = 14.4 KB
    __shared__ float mlds[2 * MPB * DD];               // 480: [0,240)=rv2f, [240,480)=cv2f
    int f0  = blockIdx.x * MPB;
    int tid = threadIdx.x;

    const float4* src4 = reinterpret_cast<const float4*>(cost + (size_t)f0 * TILE);
    float4* dst4 = reinterpret_cast<float4*>(tile);
    // 900 float4 total: e = tid, tid+256, tid+512 always < 900; tid+768 predicated
    float4 r0 = src4[tid];
    float4 r1 = src4[tid + 256];
    float4 r2 = src4[tid + 512];
    bool p3 = (tid + 768) < (MPB * TILE / 4);
    float4 r3 = {0.f, 0.f, 0.f, 0.f};
    if (p3) r3 = src4[tid + 768];
    // msgs: 480 floats, 2-deep. e=tid; e2=tid+256 (always lands in cv2f half)
    float s0 = (tid < MPB * DD) ? msgs[(size_t)f0 * DD + tid]
                                : msgs[(size_t)(F_N + f0) * DD + (tid - MPB * DD)];
    bool pm = (tid + 256) < 2 * MPB * DD;
    float s1 = 0.0f;
    if (pm) s1 = msgs[(size_t)(F_N + f0) * DD + (tid + 256 - MPB * DD)];

    dst4[tid]       = r0;
    dst4[tid + 256] = r1;
    dst4[tid + 512] = r2;
    if (p3) dst4[tid + 768] = r3;
    mlds[tid] = s0;
    if (pm) mlds[tid + 256] = s1;
    __syncthreads();

    int r = tid & 31;          // 0..29 active
#pragma unroll
    for (int h = 0; h < 2; ++h) {
        int q = (tid >> 5) + 8 * h;      // factor within block (0..15)
        if (r < 30) {
            bool is_row = (r < DD);
            int i = is_row ? r : (r - DD);
            int f = f0 + q;
            // m_f2rv (row-min over j) uses m_cv2f = msgs[F_N+f]; m_f2cv uses m_rv2f = msgs[f]
            const float* mb = is_row ? &mlds[MPB * DD + q * DD] : &mlds[q * DD];
            const float* Cf = &tile[q * TILE];
            float mn = 1e30f;
#pragma unroll
            for (int k = 0; k < DD; ++k) {
                int a = is_row ? (i * DD + k) : (k * DD + i);
                mn = fminf(mn, Cf[a] + mb[k]);
            }
            size_t t = is_row ? (size_t)f : (size_t)(F_N + f);
            m_arr[t * DP + i] = mn;
        }
    }
}

// 16 lanes per variable: lane k owns belief[k]. Bucket indices prefetched
// (coalesced) and broadcast via shfl; m-row loads independent.
// Softmax/entropy/argmax via width-16 shfl_xor butterflies.
// Entropy: wave reduce -> LDS -> ONE atomic per block into 256 spread slots.
__global__ __launch_bounds__(256) void k_gather_softmax(
        const float* __restrict__ m,
        const int* __restrict__ cnt,
        const int* __restrict__ tlist,
        float* __restrict__ dist,
        int*   __restrict__ amax,
        float* __restrict__ slotE) {
    int gid = blockIdx.x * 256 + threadIdx.x;
    int v = gid >> 4;
    int k = gid & 15;
    bool act = (v < V_N) && (k < DD);
    float b0 = 0.0f, b1 = 0.0f;
    if (v < V_N) {
        int n = cnt[v];
        if (n > CAP) n = CAP;
        int n1 = (n < 16) ? n : 16;
        int tl  = (k < n)       ? tlist[v * CAP + k]      : 0;
        int tl2 = (k + 16 < n)  ? tlist[v * CAP + k + 16] : 0;
        int i = 0;
        for (; i + 1 < n1; i += 2) {
            int ta = __shfl(tl, i, 16);
            int tb = __shfl(tl, i + 1, 16);
            if (k < DD) {
                b0 += m[(size_t)ta * DP + k];
                b1 += m[(size_t)tb * DP + k];
            }
        }
        if (i < n1) {
            int ta = __shfl(tl, i, 16);
            if (k < DD) b0 += m[(size_t)ta * DP + k];
        }
        for (int j = 16; j < n; ++j) {          // rare: deg > 16
            int ta = __shfl(tl2, j - 16, 16);
            if (k < DD) b1 += m[(size_t)ta * DP + k];
        }
    }
    float b = b0 + b1;
    float bm = act ? b : 1e30f;
#pragma unroll
    for (int off = 1; off < 16; off <<= 1) bm = fminf(bm, __shfl_xor(bm, off, 16));
    float e = act ? expf(bm - b) : 0.0f;
    float den = e;
#pragma unroll
    for (int off = 1; off < 16; off <<= 1) den += __shfl_xor(den, off, 16);
    float dk = e / den;
    float entp = 0.0f;
    if (act) {
        dist[(size_t)v * DP + k] = dk;
        entp = -dk * log2f(dk + 1e-6f);
    }
    // argmax with first-max (lowest index on tie) semantics
    float av = act ? dk : -1.0f;
    int   ai = k;
#pragma unroll
    for (int off = 1; off < 16; off <<= 1) {
        float ov = __shfl_xor(av, off, 16);
        int   oi = __shfl_xor(ai, off, 16);
        if (ov > av || (ov == av && oi < ai)) { av = ov; ai = oi; }
    }
    if (k == 0 && v < V_N) amax[v] = ai;
#pragma unroll
    for (int off = 32; off > 0; off >>= 1) entp += __shfl_down(entp, off, 64);
    __shared__ float sE[4];
    if ((threadIdx.x & 63) == 0) sE[threadIdx.x >> 6] = entp;
    __syncthreads();
    if (threadIdx.x == 0)
        atomicAdd(&slotE[blockIdx.x & (NSLOT - 1)], sE[0] + sE[1] + sE[2] + sE[3]);
}

// One wave per factor: per_f = drv^T C dcv, cost = C[amax,amax].
// dist rows loaded ONCE (broadcast cacheline), spread to elements via shfl.
__global__ __launch_bounds__(256) void k_factor_loss(
        const float* __restrict__ cost,
        const float* __restrict__ dist,
        const int*   __restrict__ amax,
        const int*   __restrict__ rv_idx,
        const int*   __restrict__ cv_idx,
        float* __restrict__ slotP,
        float* __restrict__ slotC) {
    int gtid = blockIdx.x * 256 + threadIdx.x;
    int f    = gtid >> 6;
    int lane = threadIdx.x & 63;
    float s = 0.0f, c = 0.0f;
    if (f < F_N) {
        int rv = rv_idx[f], cv = cv_idx[f];
        float drv = dist[(size_t)rv * DP + (lane & 15)];
        float dcv = dist[(size_t)cv * DP + (lane & 15)];
        const float* Cf = cost + (size_t)f * TILE;
#pragma unroll
        for (int t = 0; t < 4; ++t) {
            int e = lane + t * 64;
            if (e < TILE) {
                int i = e / DD;
                int j = e - i * DD;
                s += __shfl(drv, i, 64) * Cf[e] * __shfl(dcv, j, 64);
            }
        }
        if (lane == 0) c = Cf[amax[rv] * DD + amax[cv]];
    }
#pragma unroll
    for (int off = 32; off > 0; off >>= 1) s += __shfl_down(s, off, 64);
    __shared__ float sP[4], sC[4];
    int w = threadIdx.x >> 6;
    if (lane == 0) { sP[w] = s; sC[w] = c; }
    __syncthreads();
    if (threadIdx.x == 0) {
        float tp = sP[0] + sP[1] + sP[2] + sP[3];
        float tc = sC[0] + sC[1] + sC[2] + sC[3];
        int slot = blockIdx.x & (NSLOT - 1);
        atomicAdd(&slotP[slot], tp);
        atomicAdd(&slotC[slot], tc);
    }
}

__global__ void k_final(const float* __restrict__ slotP,
                        const float* __restrict__ slotC,
                        const float* __restrict__ slotE,
                        float* __restrict__ out) {
    int t = threadIdx.x;   // 256 threads
    float p = slotP[t], c = slotC[t], g = slotE[t];
#pragma unroll
    for (int off = 32; off > 0; off >>= 1) {
        p += __shfl_down(p, off, 64);
        c += __shfl_down(c, off, 64);
        g += __shfl_down(g, off, 64);
    }
    __shared__ float sp[4], sc[4], se[4];
    if ((t & 63) == 0) { sp[t >> 6] = p; sc[t >> 6] = c; se[t >> 6] = g; }
    __syncthreads();
    if (t == 0) {
        float tp = sp[0] + sp[1] + sp[2] + sp[3];
        float tc = sc[0] + sc[1] + sc[2] + sc[3];
        float te = se[0] + se[1] + se[2] + se[3];
        out[0] = tp + 0.1f * (te / (float)V_N);
        out[1] = tc;
    }
}

extern "C" void kernel_launch(void* const* d_in, const int* in_sizes, int n_in,
                              void* d_out, int out_size, void* d_ws, size_t ws_size,
                              hipStream_t stream) {
    const float* msgs = (const float*)d_in[0];   // (4*F_N, 15)
    const float* cost = (const float*)d_in[1];   // (F_N, 15, 15)
    const int* scat   = (const int*)d_in[46];    // f2v_per_v_scatter_idxes (2*F_N)
    const int* rv     = (const int*)d_in[48];    // rv_idxes (F_N)
    const int* cv     = (const int*)d_in[49];    // cv_idxes (F_N)

    float* ws    = (float*)d_ws;
    float* m     = ws + M_OFF;
    float* dist  = ws + DIST_OFF;
    int*   cnt   = (int*)(ws + CNT_OFF);
    int*   tlist = (int*)(ws + TLIST_OFF);
    int*   amax  = (int*)(ws + AMAX_OFF);
    float* slotP = ws + SLOTP_OFF;
    float* slotC = ws + SLOTC_OFF;
    float* slotE = ws + SLOTE_OFF;
    float* out   = (float*)d_out;

    k_init<<<(V_N + 255) / 256, 256, 0, stream>>>(cnt, slotP);
    k_place<<<(T_N + 255) / 256, 256, 0, stream>>>(scat, cnt, tlist);
    k_minplus<<<F_N / MPB, 256, 0, stream>>>(msgs, cost, m);
    k_gather_softmax<<<(V_N * 16 + 255) / 256, 256, 0, stream>>>(m, cnt, tlist, dist, amax, slotE);
    k_factor_loss<<<(F_N * 64 + 255) / 256, 256, 0, stream>>>(cost, dist, amax, rv, cv, slotP, slotC);
    k_final<<<1, 256, 0, stream>>>(slotP, slotC, slotE, out);
}

// Round 10
// 94.168 us; speedup vs baseline: 1.0589x; 1.0036x over previous
//
#include <hip/hip_runtime.h>

#define F_N 100000
#define V_N 30000
#define DD 15          // domain size D
#define DP 16          // padded row stride (64 B / cacheline)
#define TILE 225       // D*D
#define T_N (2 * F_N)  // 200000 f2v messages
#define NSLOT 256
#define MPB 16         // factors per block in minplus kernel
#define CAP 32         // bucket capacity per variable

// ---- workspace layout (float offsets) ----
static const size_t M_OFF     = 0;          // float[T_N*DP]  = 3,200,000
static const size_t DIST_OFF  = 3200000;    // float[V_N*DP]  = 480,000
static const size_t CNT_OFF   = 3680000;    // int[V_N]
static const size_t TLIST_OFF = 3710048;    // int[V_N*CAP]   = 960,000
static const size_t AMAX_OFF  = 4670048;    // int[V_N]
static const size_t SLOTP_OFF = 4700064;    // float[NSLOT]
static const size_t SLOTC_OFF = 4700320;    // float[NSLOT]
static const size_t SLOTE_OFF = 4700576;    // float[NSLOT]

__global__ void k_init(int* __restrict__ cnt, float* __restrict__ slots) {
    int i = blockIdx.x * blockDim.x + threadIdx.x;
    if (i < V_N) cnt[i] = 0;
    if (i < 3 * NSLOT) slots[i] = 0.0f;   // slotP, slotC, slotE (contiguous)
}

// Bucket-place: invert the scatter with one int atomic per message.
__global__ void k_place(const int* __restrict__ scat,
                        int* __restrict__ cnt,
                        int* __restrict__ tlist) {
    int t = blockIdx.x * blockDim.x + threadIdx.x;
    if (t < T_N) {
        int v = scat[t];
        int pos = atomicAdd(&cnt[v], 1);
        if (pos < CAP) tlist[v * CAP + pos] = t;
    }
}

// Block handles 16 factors. Staging: manual 4-deep float4. Compute: BATCHED —
// all 15 C values + 15 msg values into register arrays (independent ds_reads
// issued together), then a 2-chain fmin tree. launch_bounds(256,2) gives the
// register allocator room (<=128 VGPR) so loads actually batch.
__global__ __launch_bounds__(256, 2) void k_minplus(
        const float* __restrict__ msgs,
        const float* __restrict__ cost,
        float* __restrict__ m_arr) {
    __shared__ __align__(16) float tile[MPB * TILE];   // 3600 floats = 14.4 KB
    __shared__ float mlds[2 * MPB * DD];               // 480: [0,240)=rv2f, [240,480)=cv2f
    int f0  = blockIdx.x * MPB;
    int tid = threadIdx.x;

    const float4* src4 = reinterpret_cast<const float4*>(cost + (size_t)f0 * TILE);
    float4* dst4 = reinterpret_cast<float4*>(tile);
    float4 r0 = src4[tid];
    float4 r1 = src4[tid + 256];
    float4 r2 = src4[tid + 512];
    bool p3 = (tid + 768) < (MPB * TILE / 4);
    float4 r3 = {0.f, 0.f, 0.f, 0.f};
    if (p3) r3 = src4[tid + 768];
    float s0 = (tid < MPB * DD) ? msgs[(size_t)f0 * DD + tid]
                                : msgs[(size_t)(F_N + f0) * DD + (tid - MPB * DD)];
    bool pm = (tid + 256) < 2 * MPB * DD;
    float s1 = 0.0f;
    if (pm) s1 = msgs[(size_t)(F_N + f0) * DD + (tid + 256 - MPB * DD)];

    dst4[tid]       = r0;
    dst4[tid + 256] = r1;
    dst4[tid + 512] = r2;
    if (p3) dst4[tid + 768] = r3;
    mlds[tid] = s0;
    if (pm) mlds[tid + 256] = s1;
    __syncthreads();

    int r = tid & 31;          // 0..29 active
#pragma unroll
    for (int h = 0; h < 2; ++h) {
        int q = (tid >> 5) + 8 * h;      // factor within block (0..15)
        if (r < 30) {
            bool is_row = (r < DD);
            int i = is_row ? r : (r - DD);
            int f = f0 + q;
            // m_f2rv (row-min over j) uses m_cv2f = msgs[F_N+f]; m_f2cv uses m_rv2f
            const float* mb = is_row ? &mlds[MPB * DD + q * DD] : &mlds[q * DD];
            const float* Cf = &tile[q * TILE];
            float c[DD], g[DD];
#pragma unroll
            for (int k = 0; k < DD; ++k)
                c[k] = Cf[is_row ? (i * DD + k) : (k * DD + i)];
#pragma unroll
            for (int k = 0; k < DD; ++k)
                g[k] = mb[k];
            float mn0 = 1e30f, mn1 = 1e30f;
#pragma unroll
            for (int k = 0; k < DD; k += 2) mn0 = fminf(mn0, c[k] + g[k]);
#pragma unroll
            for (int k = 1; k < DD; k += 2) mn1 = fminf(mn1, c[k] + g[k]);
            float mn = fminf(mn0, mn1);
            size_t t = is_row ? (size_t)f : (size_t)(F_N + f);
            m_arr[t * DP + i] = mn;
        }
    }
}

// 16 lanes per variable: lane k owns belief[k]. Bucket indices loaded by ALL
// lanes (same-address broadcast loads, no shfl chain), batched 8-wide; the 8
// m-row loads are then independent. Softmax/entropy/argmax via width-16
// butterflies; entropy via one block atomic into 256 spread slots.
__global__ __launch_bounds__(256, 2) void k_gather_softmax(
        const float* __restrict__ m,
        const int* __restrict__ cnt,
        const int* __restrict__ tlist,
        float* __restrict__ dist,
        int*   __restrict__ amax,
        float* __restrict__ slotE) {
    int gid = blockIdx.x * 256 + threadIdx.x;
    int v = gid >> 4;
    int k = gid & 15;
    bool act = (v < V_N) && (k < DD);
    float b = 0.0f;
    if (v < V_N) {
        int n = cnt[v];
        if (n > CAP) n = CAP;
        for (int j0 = 0; j0 < n; j0 += 8) {
            int nj = n - j0; if (nj > 8) nj = 8;
            int tj[8];
#pragma unroll
            for (int j = 0; j < 8; ++j)
                tj[j] = (j < nj) ? tlist[v * CAP + j0 + j] : 0;
            float mv[8];
#pragma unroll
            for (int j = 0; j < 8; ++j)
                mv[j] = (j < nj && k < DD) ? m[(size_t)tj[j] * DP + k] : 0.0f;
#pragma unroll
            for (int j = 0; j < 8; ++j) b += mv[j];
        }
    }
    float bm = act ? b : 1e30f;
#pragma unroll
    for (int off = 1; off < 16; off <<= 1) bm = fminf(bm, __shfl_xor(bm, off, 16));
    float e = act ? expf(bm - b) : 0.0f;
    float den = e;
#pragma unroll
    for (int off = 1; off < 16; off <<= 1) den += __shfl_xor(den, off, 16);
    float dk = e / den;
    float entp = 0.0f;
    if (act) {
        dist[(size_t)v * DP + k] = dk;
        entp = -dk * log2f(dk + 1e-6f);
    }
    // argmax with first-max (lowest index on tie) semantics
    float av = act ? dk : -1.0f;
    int   ai = k;
#pragma unroll
    for (int off = 1; off < 16; off <<= 1) {
        float ov = __shfl_xor(av, off, 16);
        int   oi = __shfl_xor(ai, off, 16);
        if (ov > av || (ov == av && oi < ai)) { av = ov; ai = oi; }
    }
    if (k == 0 && v < V_N) amax[v] = ai;
#pragma unroll
    for (int off = 32; off > 0; off >>= 1) entp += __shfl_down(entp, off, 64);
    __shared__ float sE[4];
    if ((threadIdx.x & 63) == 0) sE[threadIdx.x >> 6] = entp;
    __syncthreads();
    if (threadIdx.x == 0)
        atomicAdd(&slotE[blockIdx.x & (NSLOT - 1)], sE[0] + sE[1] + sE[2] + sE[3]);
}

// One wave per factor: per_f = drv^T C dcv, cost = C[amax,amax].
// dist rows loaded ONCE (broadcast cacheline), spread via shfl.
__global__ __launch_bounds__(256, 2) void k_factor_loss(
        const float* __restrict__ cost,
        const float* __restrict__ dist,
        const int*   __restrict__ amax,
        const int*   __restrict__ rv_idx,
        const int*   __restrict__ cv_idx,
        float* __restrict__ slotP,
        float* __restrict__ slotC) {
    int gtid = blockIdx.x * 256 + threadIdx.x;
    int f    = gtid >> 6;
    int lane = threadIdx.x & 63;
    float s = 0.0f, c = 0.0f;
    if (f < F_N) {
        int rv = rv_idx[f], cv = cv_idx[f];
        float drv = dist[(size_t)rv * DP + (lane & 15)];
        float dcv = dist[(size_t)cv * DP + (lane & 15)];
        const float* Cf = cost + (size_t)f * TILE;
        float cf[4];
#pragma unroll
        for (int t = 0; t < 4; ++t) {
            int e = lane + t * 64;
            cf[t] = (e < TILE) ? Cf[e] : 0.0f;
        }
#pragma unroll
        for (int t = 0; t < 4; ++t) {
            int e = lane + t * 64;
            if (e < TILE) {
                int i = e / DD;
                int j = e - i * DD;
                s += __shfl(drv, i, 64) * cf[t] * __shfl(dcv, j, 64);
            }
        }
        if (lane == 0) c = Cf[amax[rv] * DD + amax[cv]];
    }
#pragma unroll
    for (int off = 32; off > 0; off >>= 1) s += __shfl_down(s, off, 64);
    __shared__ float sP[4], sC[4];
    int w = threadIdx.x >> 6;
    if (lane == 0) { sP[w] = s; sC[w] = c; }
    __syncthreads();
    if (threadIdx.x == 0) {
        float tp = sP[0] + sP[1] + sP[2] + sP[3];
        float tc = sC[0] + sC[1] + sC[2] + sC[3];
        int slot = blockIdx.x & (NSLOT - 1);
        atomicAdd(&slotP[slot], tp);
        atomicAdd(&slotC[slot], tc);
    }
}

__global__ void k_final(const float* __restrict__ slotP,
                        const float* __restrict__ slotC,
                        const float* __restrict__ slotE,
                        float* __restrict__ out) {
    int t = threadIdx.x;   // 256 threads
    float p = slotP[t], c = slotC[t], g = slotE[t];
#pragma unroll
    for (int off = 32; off > 0; off >>= 1) {
        p += __shfl_down(p, off, 64);
        c += __shfl_down(c, off, 64);
        g += __shfl_down(g, off, 64);
    }
    __shared__ float sp[4], sc[4], se[4];
    if ((t & 63) == 0) { sp[t >> 6] = p; sc[t >> 6] = c; se[t >> 6] = g; }
    __syncthreads();
    if (t == 0) {
        float tp = sp[0] + sp[1] + sp[2] + sp[3];
        float tc = sc[0] + sc[1] + sc[2] + sc[3];
        float te = se[0] + se[1] + se[2] + se[3];
        out[0] = tp + 0.1f * (te / (float)V_N);
        out[1] = tc;
    }
}

extern "C" void kernel_launch(void* const* d_in, const int* in_sizes, int n_in,
                              void* d_out, int out_size, void* d_ws, size_t ws_size,
                              hipStream_t stream) {
    const float* msgs = (const float*)d_in[0];   // (4*F_N, 15)
    const float* cost = (const float*)d_in[1];   // (F_N, 15, 15)
    const int* scat   = (const int*)d_in[46];    // f2v_per_v_scatter_idxes (2*F_N)
    const int* rv     = (const int*)d_in[48];    // rv_idxes (F_N)
    const int* cv     = (const int*)d_in[49];    // cv_idxes (F_N)

    float* ws    = (float*)d_ws;
    float* m     = ws + M_OFF;
    float* dist  = ws + DIST_OFF;
    int*   cnt   = (int*)(ws + CNT_OFF);
    int*   tlist = (int*)(ws + TLIST_OFF);
    int*   amax  = (int*)(ws + AMAX_OFF);
    float* slotP = ws + SLOTP_OFF;
    float* slotC = ws + SLOTC_OFF;
    float* slotE = ws + SLOTE_OFF;
    float* out   = (float*)d_out;

    k_init<<<(V_N + 255) / 256, 256, 0, stream>>>(cnt, slotP);
    k_place<<<(T_N + 255) / 256, 256, 0, stream>>>(scat, cnt, tlist);
    k_minplus<<<F_N / MPB, 256, 0, stream>>>(msgs, cost, m);
    k_gather_softmax<<<(V_N * 16 + 255) / 256, 256, 0, stream>>>(m, cnt, tlist, dist, amax, slotE);
    k_factor_loss<<<(F_N * 64 + 255) / 256, 256, 0, stream>>>(cost, dist, amax, rv, cv, slotP, slotC);
    k_final<<<1, 256, 0, stream>>>(slotP, slotC, slotE, out);
}